// Round 17
// baseline (2724.600 us; speedup 1.0000x reference)
//
#include <hip/hip_runtime.h>
#include <stdint.h>

// Problem constants
#define BB   128
#define DD   512
#define HH   1024
#define SS   512
#define G4   4096
#define KKT  48       // (D+H)/32 k-steps: kk 0..15 = x, 16..47 = h
#define NT_FC 64
#define KK_FC 32
#define HSTEP 131072  // shorts per h snapshot (BB*HH)

typedef __attribute__((ext_vector_type(8))) short short8v;
typedef __attribute__((ext_vector_type(4))) float float4v;
typedef __attribute__((ext_vector_type(4))) unsigned int uint4v;

__device__ __forceinline__ unsigned short f2bf(float f) {
    union { float f; unsigned int u; } v; v.f = f;
    unsigned int u = v.u;
    unsigned int r = u + 0x7FFFu + ((u >> 16) & 1u);   // RNE
    return (unsigned short)(r >> 16);
}
__device__ __forceinline__ float sigm(float z) { return 1.f / (1.f + __expf(-z)); }
__device__ __forceinline__ float tanh_f(float z) { float e = __expf(2.f * z); return 1.f - 2.f / (e + 1.f); }

__device__ __forceinline__ short8v cvt8(const float4 f0, const float4 f1) {
    short8v o;
    o[0]=(short)f2bf(f0.x); o[1]=(short)f2bf(f0.y); o[2]=(short)f2bf(f0.z); o[3]=(short)f2bf(f0.w);
    o[4]=(short)f2bf(f1.x); o[5]=(short)f2bf(f1.y); o[6]=(short)f2bf(f1.z); o[7]=(short)f2bf(f1.w);
    return o;
}

// ---------------------------------------------------------------------------
// Pack W = [W_ih | W_hh] into bf16 MFMA fragment order, q-major n-tiles:
// ntile = q*64 + jg -> W row = q*H + jg*16 + (lane&15), k = kk*32+(lane>>4)*8
// ---------------------------------------------------------------------------
__global__ void pack_w_kernel(const float* __restrict__ W_ih,
                              const float* __restrict__ W_hh,
                              unsigned short* __restrict__ wp) {
    int idx = blockIdx.x * 256 + threadIdx.x;
    if (idx >= 256 * KKT * 64) return;
    int lane  = idx & 63;
    int kk    = (idx >> 6) % KKT;
    int ntile = idx / (64 * KKT);
    int q = ntile >> 6;
    int orow = q * HH + (ntile & 63) * 16 + (lane & 15);
    int kbase = kk * 32 + (lane >> 4) * 8;
    short8v ov;
#pragma unroll
    for (int i = 0; i < 8; ++i) {
        int k = kbase + i;
        float v = (k < DD) ? W_ih[(size_t)orow * DD + k]
                           : W_hh[(size_t)orow * HH + (k - DD)];
        ov[i] = (short)f2bf(v);
    }
    *(short8v*)&wp[(size_t)idx * 8] = ov;
}

__global__ void pack_fc_kernel(const float* __restrict__ fc_w,
                               unsigned short* __restrict__ wfc) {
    int idx = blockIdx.x * 256 + threadIdx.x;
    if (idx >= NT_FC * KK_FC * 64) return;
    int lane  = idx & 63;
    int kk    = (idx >> 6) % KK_FC;
    int ntile = idx / (64 * KK_FC);
    int o = ntile * 16 + (lane & 15);
    int kbase = kk * 32 + (lane >> 4) * 8;
    short8v ov;
#pragma unroll
    for (int i = 0; i < 8; ++i)
        ov[i] = (short)f2bf(fc_w[(size_t)o * HH + kbase + i]);
    *(short8v*)&wfc[(size_t)idx * 8] = ov;
}

// x -> bf16 MFMA A-fragment order: xpre[((mtile*S + t)*16 + kk)*64 + lane]
// mtile = batch/16 = chain
__global__ void pack_x_kernel(const float* __restrict__ x,
                              unsigned short* __restrict__ xpre) {
    int idx = blockIdx.x * 256 + threadIdx.x;
    if (idx >= 8 * SS * 16 * 64) return;
    int lane  = idx & 63;
    int kk    = (idx >> 6) & 15;
    int t     = (idx >> 10) & (SS - 1);
    int mtile = idx >> 19;
    int b = mtile * 16 + (lane & 15);
    int d = kk * 32 + (lane >> 4) * 8;
    const float* src = &x[((size_t)b * SS + t) * DD + d];
    short8v ov;
#pragma unroll
    for (int i = 0; i < 8; ++i) ov[i] = (short)f2bf(src[i]);
    *(short8v*)&xpre[(size_t)idx * 8] = ov;
}

// zero h(0) + barrier slots, pack bias bp[j*4+q] = b_ih[q*H+j] + b_hh[q*H+j]
__global__ void init_kernel(const float* __restrict__ b_ih,
                            const float* __restrict__ b_hh,
                            unsigned short* __restrict__ h0,
                            float* __restrict__ bpp,
                            unsigned int* __restrict__ bar) {
    int i = blockIdx.x * 256 + threadIdx.x;
    if (i < BB * HH) h0[i] = 0;
    if (i < G4) { int j = i >> 2, q = i & 3; bpp[i] = b_ih[q * HH + j] + b_hh[q * HH + j]; }
    if (i < 4096) bar[i] = 0;
}

// ---------------------------------------------------------------------------
// Persistent LSTM: 512 WGs (2/CU) = 8 chains (16 batch rows) x 64 WGs (16 j).
// Wave = gate q, 1 ntile, M=16. W: kk0..15 VGPR, kk16..27 LDS, kk28..47 L2.
// HIST=1: every step writes a FRESH h buffer hh[t+1] (sc0/sc1 write-through);
// readers use normal CACHED loads. ANTI-PHASE SEED: chains 4..7 start ~2.3us
// late. NEW vs champion: stage split in halves — half-B loads issue early and
// ride under half-A MFMAs (isolated R14 component, publish-early kept).
// ---------------------------------------------------------------------------
template<int PRE, int HIST>
__launch_bounds__(256, 2)
__global__ void lstm_persist(const float* __restrict__ x,
                             const unsigned short* __restrict__ xpre,
                             const unsigned short* __restrict__ wp,
                             const float* __restrict__ bp,
                             unsigned short* hh,          // HIST: base of SS+1 snapshots; else buf0
                             unsigned short* hbufB,       // HIST unused; else buf1
                             unsigned int* bar) {
    __shared__ __align__(16) unsigned short whl[4 * 12 * 64 * 8]; // 48 KiB W kk16..27
    __shared__ __align__(16) unsigned short hl[32 * 64 * 8];      // 32 KiB h frags (linear)
    float* gl = (float*)hl;                                       // gate exchange alias

    const int tid  = threadIdx.x;
    const int bid  = blockIdx.x;
    const int chain = bid >> 6;                 // 0..7 (16 batch rows each)
    const int jg    = bid & 63;                 // jg%8 = XCD for every chain
    const int lane = tid & 63;
    const int w    = tid >> 6;                  // wave = gate q
    const int l15  = lane & 15;
    const int lhi  = lane >> 4;

    // ---- resident W kk0..15 (64 VGPRs), pinned ----
    const size_t ntb = (size_t)(w * 64 + jg) * KKT;
    short8v wx[16];
#pragma unroll
    for (int kk = 0; kk < 16; ++kk)
        wx[kk] = *(const short8v*)&wp[((ntb + kk) * 64 + lane) * 8];
#pragma unroll
    for (int kk = 0; kk < 16; ++kk)
        asm volatile("" : "+v"(wx[kk]));

    // ---- LDS W kk16..27 (4 ntiles x 12 kk), loaded once ----
#pragma unroll
    for (int i = 0; i < 12; ++i) {
        int f  = tid + 256 * i;                 // 0..3071 16B frags
        int ln = f & 63, kkl = (f >> 6) % 12, wq = (f >> 6) / 12;
        *(short8v*)&whl[(size_t)f * 8] =
            *(const short8v*)&wp[(((size_t)(wq * 64 + jg) * KKT + 16 + kkl) * 64 + ln) * 8];
    }

    // ---- epilogue constants (tid < 128 active): row = tid>>3, units up,up+1 ----
    const int erow = (tid & 127) >> 3;
    const int eup  = (tid & 7) * 2;
    const float4 eb0 = *(const float4*)&bp[(jg * 16 + eup) * 4];
    const float4 eb1 = *(const float4*)&bp[(jg * 16 + eup + 1) * 4];
    float ec0 = 0.f, ec1 = 0.f;
    // frag-major h store offset (shorts) within a snapshot
    const int ekkh = jg >> 1;
    const int esub = (jg & 1) * 2 + (eup >> 3);
    const size_t esoff = ((size_t)(chain * 32 + ekkh) * 64 + (esub * 16 + erow)) * 8 + (eup & 7);

    __syncthreads();                            // whl ready

    // ---- anti-phase seed: stagger co-resident chain pairs by ~half a step ----
    if (chain >= 4) {
#pragma unroll 1
        for (int i = 0; i < 6; ++i) __builtin_amdgcn_s_sleep(15);
    }

#pragma unroll 1
    for (int t = 0; t < SS; ++t) {
        const unsigned short* hin;
        unsigned short* hout;
        if (HIST) {
            hin  = hh + (size_t)t * HSTEP;
            hout = hh + (size_t)(t + 1) * HSTEP;
        } else {
            hin  = (t & 1) ? hbufB : hh;
            hout = (t & 1) ? hh : hbufB;
        }

        __syncthreads();                        // S2: prev h stores acked by all

        // ---- arrive: publish "h(t-1) visible" ----
        if (t > 0 && tid == 0)
            __hip_atomic_store(&bar[chain * 64 + jg], (unsigned int)t,
                               __ATOMIC_RELAXED, __HIP_MEMORY_SCOPE_AGENT);

        float4v acce = {0.f, 0.f, 0.f, 0.f};
        float4v acco = {0.f, 0.f, 0.f, 0.f};

        // ---- x-phase (kk 0..15) — no h dependence, overlaps barrier ----
#pragma unroll
        for (int kk = 0; kk < 16; kk += 2) {
            short8v a0, a1;
            if (PRE) {
                a0 = *(const short8v*)&xpre[(((size_t)(chain * SS + t) * 16 + kk) * 64 + lane) * 8];
                a1 = *(const short8v*)&xpre[(((size_t)(chain * SS + t) * 16 + kk + 1) * 64 + lane) * 8];
            } else {
                const float* p0 = &x[((size_t)(chain * 16 + l15) * SS + t) * DD + kk * 32 + lhi * 8];
                a0 = cvt8(*(const float4*)p0, *(const float4*)(p0 + 4));
                a1 = cvt8(*(const float4*)(p0 + 32), *(const float4*)(p0 + 36));
            }
            acce = __builtin_amdgcn_mfma_f32_16x16x32_bf16(a0, wx[kk], acce, 0, 0, 0);
            acco = __builtin_amdgcn_mfma_f32_16x16x32_bf16(a1, wx[kk + 1], acco, 0, 0, 0);
        }

        // ---- barrier wait: wave 0 polls the chain's 64 packed slots ----
        if (t > 0 && w == 0) {
            const unsigned int tgt = (unsigned int)t;
            for (;;) {
                unsigned int v = __hip_atomic_load(&bar[chain * 64 + lane],
                                                   __ATOMIC_RELAXED, __HIP_MEMORY_SCOPE_AGENT);
                if (!__any(v < tgt)) break;
                __builtin_amdgcn_s_sleep(1);
            }
        }
        __syncthreads();                        // S3: h(t-1) globally visible

        // ---- stage half A (kkh 0..15): 64B/thread, conflict-free ----
        const char* hsrc = (const char*)hin + (size_t)chain * 32768 + (size_t)tid * 16;
        char* ldst = (char*)hl + (size_t)tid * 16;
        if (HIST) {
            uint4v r0 = *(const uint4v*)(hsrc);
            uint4v r1 = *(const uint4v*)(hsrc + 4096);
            uint4v r2 = *(const uint4v*)(hsrc + 8192);
            uint4v r3 = *(const uint4v*)(hsrc + 12288);
            *(uint4v*)(ldst)         = r0;
            *(uint4v*)(ldst + 4096)  = r1;
            *(uint4v*)(ldst + 8192)  = r2;
            *(uint4v*)(ldst + 12288) = r3;
        } else {
            uint4v r0,r1,r2,r3;
            asm volatile("global_load_dwordx4 %0, %1, off sc0 sc1" : "=v"(r0) : "v"(hsrc));
            asm volatile("global_load_dwordx4 %0, %1, off sc0 sc1" : "=v"(r1) : "v"(hsrc + 4096));
            asm volatile("global_load_dwordx4 %0, %1, off sc0 sc1" : "=v"(r2) : "v"(hsrc + 8192));
            asm volatile("global_load_dwordx4 %0, %1, off sc0 sc1" : "=v"(r3) : "v"(hsrc + 12288));
            asm volatile("s_waitcnt vmcnt(0)" ::: "memory");
            __builtin_amdgcn_sched_barrier(0);
            *(uint4v*)(ldst)         = r0;
            *(uint4v*)(ldst + 4096)  = r1;
            *(uint4v*)(ldst + 8192)  = r2;
            *(uint4v*)(ldst + 12288) = r3;
        }
        __syncthreads();                        // S4a: kkh 0..15 ready

        // ---- issue half-B loads (kkh 16..31) — ride under half-A MFMAs ----
        uint4v rb0, rb1, rb2, rb3;
        if (HIST) {
            rb0 = *(const uint4v*)(hsrc + 16384);
            rb1 = *(const uint4v*)(hsrc + 20480);
            rb2 = *(const uint4v*)(hsrc + 24576);
            rb3 = *(const uint4v*)(hsrc + 28672);
        } else {
            asm volatile("global_load_dwordx4 %0, %1, off sc0 sc1" : "=v"(rb0) : "v"(hsrc + 16384));
            asm volatile("global_load_dwordx4 %0, %1, off sc0 sc1" : "=v"(rb1) : "v"(hsrc + 20480));
            asm volatile("global_load_dwordx4 %0, %1, off sc0 sc1" : "=v"(rb2) : "v"(hsrc + 24576));
            asm volatile("global_load_dwordx4 %0, %1, off sc0 sc1" : "=v"(rb3) : "v"(hsrc + 28672));
        }
        asm volatile("" : "+v"(rb0), "+v"(rb1), "+v"(rb2), "+v"(rb3));  // force early issue

        // ---- h-phase half A (kkh 0..15): whl for kkh<12, streamed beyond ----
#pragma unroll
        for (int kkh = 0; kkh < 16; kkh += 2) {
            short8v a0 = *(const short8v*)((char*)hl + kkh * 1024 + lane * 16);
            short8v a1 = *(const short8v*)((char*)hl + (kkh + 1) * 1024 + lane * 16);
            short8v b0, b1;
            if (kkh < 12) b0 = *(const short8v*)&whl[(size_t)((w * 12 + kkh) * 64 + lane) * 8];
            else          b0 = *(const short8v*)&wp[((ntb + 16 + kkh) * 64 + lane) * 8];
            if (kkh + 1 < 12) b1 = *(const short8v*)&whl[(size_t)((w * 12 + kkh + 1) * 64 + lane) * 8];
            else              b1 = *(const short8v*)&wp[((ntb + 16 + kkh + 1) * 64 + lane) * 8];
            acce = __builtin_amdgcn_mfma_f32_16x16x32_bf16(a0, b0, acce, 0, 0, 0);
            acco = __builtin_amdgcn_mfma_f32_16x16x32_bf16(a1, b1, acco, 0, 0, 0);
        }

        // ---- write half B (loads have had the whole half-A to land) ----
        if (!HIST) asm volatile("s_waitcnt vmcnt(0)" ::: "memory");
        *(uint4v*)(ldst + 16384) = rb0;
        *(uint4v*)(ldst + 20480) = rb1;
        *(uint4v*)(ldst + 24576) = rb2;
        *(uint4v*)(ldst + 28672) = rb3;
        __syncthreads();                        // S4b: kkh 16..31 ready

        // ---- h-phase half B (kkh 16..31), streamed W ----
#pragma unroll
        for (int kkh = 16; kkh < 32; kkh += 2) {
            short8v a0 = *(const short8v*)((char*)hl + kkh * 1024 + lane * 16);
            short8v a1 = *(const short8v*)((char*)hl + (kkh + 1) * 1024 + lane * 16);
            short8v b0 = *(const short8v*)&wp[((ntb + 16 + kkh) * 64 + lane) * 8];
            short8v b1 = *(const short8v*)&wp[((ntb + 16 + kkh + 1) * 64 + lane) * 8];
            acce = __builtin_amdgcn_mfma_f32_16x16x32_bf16(a0, b0, acce, 0, 0, 0);
            acco = __builtin_amdgcn_mfma_f32_16x16x32_bf16(a1, b1, acco, 0, 0, 0);
        }
        __syncthreads();                        // S5: hl dead -> gl alias safe

        // ---- gate exchange: gl[row][unit*4 + q] (16 x 68 floats) ----
#pragma unroll
        for (int r = 0; r < 4; ++r)
            gl[(lhi * 4 + r) * 68 + l15 * 4 + w] = acce[r] + acco[r];
        __syncthreads();                        // S6: gates ready

        // ---- fused activation + state (tid<128), frag-major h store + ack ----
        if (tid < 128) {
            float4 g0 = *(const float4*)&gl[erow * 68 + (eup + 0) * 4];
            float4 g1 = *(const float4*)&gl[erow * 68 + (eup + 1) * 4];
            float h0v, h1v;
            {
                float ig = sigm(g0.x + eb0.x), fg = sigm(g0.y + eb0.y);
                float gg = tanh_f(g0.z + eb0.z), og = sigm(g0.w + eb0.w);
                ec0 = fg * ec0 + ig * gg; h0v = og * tanh_f(ec0);
            }
            {
                float ig = sigm(g1.x + eb1.x), fg = sigm(g1.y + eb1.y);
                float gg = tanh_f(g1.z + eb1.z), og = sigm(g1.w + eb1.w);
                ec1 = fg * ec1 + ig * gg; h1v = og * tanh_f(ec1);
            }
            unsigned int hv = (unsigned int)f2bf(h0v) | ((unsigned int)f2bf(h1v) << 16);
            const unsigned short* hp = hout + esoff;
            asm volatile("global_store_dword %0, %1, off sc0 sc1"
                         :: "v"(hp), "v"(hv) : "memory");
        }
        asm volatile("s_waitcnt vmcnt(0)" ::: "memory");   // own store acked
    }
}

// ---------------------------------------------------------------------------
// out[128,1024] = h_fin @ fc_w^T + fc_b (fp32). hfin is FRAG-MAJOR.
// 32 WGs: 2 Mg x 16 Ng; no LDS needed.
// ---------------------------------------------------------------------------
__launch_bounds__(256)
__global__ void fc_kernel(const unsigned short* __restrict__ hfin,
                          const unsigned short* __restrict__ wfc,
                          const float* __restrict__ fc_b,
                          float* __restrict__ out) {
    const int tid = threadIdx.x, bid = blockIdx.x;
    const int mg = bid >> 4;
    const int ng = bid & 15;
    const int lane = tid & 63, wave = tid >> 6;
    const int wm = wave >> 1, wn = wave & 1;

    float4v acc[2][2] = {};
#pragma unroll
    for (int kkg = 0; kkg < 32; ++kkg) {
        short8v a[2], b[2];
#pragma unroll
        for (int mtl = 0; mtl < 2; ++mtl) {
            int gm = mg * 4 + wm * 2 + mtl;     // global 16-row tile 0..7
            a[mtl] = *(const short8v*)&hfin[((size_t)(gm * 32 + kkg) * 64 + lane) * 8];
        }
#pragma unroll
        for (int nt = 0; nt < 2; ++nt) {
            int ntile = ng * 4 + wn * 2 + nt;
            b[nt] = *(const short8v*)&wfc[(((size_t)ntile * KK_FC + kkg) * 64 + lane) * 8];
        }
#pragma unroll
        for (int mtl = 0; mtl < 2; ++mtl)
#pragma unroll
            for (int nt = 0; nt < 2; ++nt)
                acc[mtl][nt] = __builtin_amdgcn_mfma_f32_16x16x32_bf16(
                    a[mtl], b[nt], acc[mtl][nt], 0, 0, 0);
    }
#pragma unroll
    for (int mtl = 0; mtl < 2; ++mtl)
#pragma unroll
        for (int nt = 0; nt < 2; ++nt)
#pragma unroll
            for (int r = 0; r < 4; ++r) {
                int mrow = mg * 64 + wm * 32 + mtl * 16 + (lane >> 4) * 4 + r;
                int o = ng * 64 + wn * 32 + nt * 16 + (lane & 15);
                out[(size_t)mrow * HH + o] = acc[mtl][nt][r] + fc_b[o];
            }
}

// ---------------------------------------------------------------------------
extern "C" void kernel_launch(void* const* d_in, const int* in_sizes, int n_in,
                              void* d_out, int out_size, void* d_ws, size_t ws_size,
                              hipStream_t stream) {
    const float* x    = (const float*)d_in[0];
    const float* W_ih = (const float*)d_in[1];
    const float* W_hh = (const float*)d_in[2];
    const float* b_ih = (const float*)d_in[3];
    const float* b_hh = (const float*)d_in[4];
    const float* fc_w = (const float*)d_in[5];
    const float* fc_b = (const float*)d_in[6];
    float* out = (float*)d_out;

    char* ws = (char*)d_ws;
    size_t off = 0;
    unsigned short* wp  = (unsigned short*)(ws + off); off += (size_t)256 * KKT * 64 * 8 * 2;     // 12.6 MB
    unsigned short* wfc = (unsigned short*)(ws + off); off += (size_t)NT_FC * KK_FC * 64 * 8 * 2; // 2 MB
    float* bp  = (float*)(ws + off); off += (size_t)G4 * 4;
    unsigned int* bar = (unsigned int*)(ws + off); off += 4096 * 4;
    unsigned short* hbase = (unsigned short*)(ws + off);         // hist OR ping-pong
    size_t hist_bytes = (size_t)(SS + 1) * HSTEP * 2;            // 134.5 MB
    size_t pp_bytes   = (size_t)2 * HSTEP * 2;                   // 512 KB
    size_t xpre_bytes = (size_t)8 * SS * 16 * 64 * 8 * 2;        // 67 MB

    const bool hist = (ws_size >= off + hist_bytes);
    size_t hb = hist ? hist_bytes : pp_bytes;
    if (ws_size < off + hb) return;
    unsigned short* xpre = (unsigned short*)(ws + off + hb);
    const bool pre = (ws_size >= off + hb + xpre_bytes);

    unsigned short* hbufB = hist ? (unsigned short*)nullptr : (hbase + HSTEP);

    pack_w_kernel<<<3072, 256, 0, stream>>>(W_ih, W_hh, wp);
    pack_fc_kernel<<<512, 256, 0, stream>>>(fc_w, wfc);
    init_kernel<<<512, 256, 0, stream>>>(b_ih, b_hh, hbase, bp, bar);
    if (pre) pack_x_kernel<<<16384, 256, 0, stream>>>(x, xpre);

    if (hist) {
        if (pre) lstm_persist<1,1><<<512, 256, 0, stream>>>(x, xpre, wp, bp, hbase, hbufB, bar);
        else     lstm_persist<0,1><<<512, 256, 0, stream>>>(x, xpre, wp, bp, hbase, hbufB, bar);
    } else {
        if (pre) lstm_persist<1,0><<<512, 256, 0, stream>>>(x, xpre, wp, bp, hbase, hbufB, bar);
        else     lstm_persist<0,0><<<512, 256, 0, stream>>>(x, xpre, wp, bp, hbase, hbufB, bar);
    }

    // final h: hist -> snapshot SS; ping-pong (SS even) -> hbase
    const unsigned short* hfin = hist ? (hbase + (size_t)SS * HSTEP) : hbase;
    fc_kernel<<<32, 256, 0, stream>>>(hfin, wfc, fc_b, out);
}

// Round 18
// 1997.897 us; speedup vs baseline: 1.3637x; 1.3637x over previous
//
#include <hip/hip_runtime.h>
#include <stdint.h>

// Problem constants
#define BB   128
#define DD   512
#define HH   1024
#define SS   512
#define G4   4096
#define KKT  48       // (D+H)/32 k-steps: kk 0..15 = x, 16..47 = h
#define NT_FC 64
#define KK_FC 32
#define HSTEP 131072  // shorts per h snapshot (BB*HH)

typedef __attribute__((ext_vector_type(8))) short short8v;
typedef __attribute__((ext_vector_type(4))) float float4v;
typedef __attribute__((ext_vector_type(4))) unsigned int uint4v;

__device__ __forceinline__ unsigned short f2bf(float f) {
    union { float f; unsigned int u; } v; v.f = f;
    unsigned int u = v.u;
    unsigned int r = u + 0x7FFFu + ((u >> 16) & 1u);   // RNE
    return (unsigned short)(r >> 16);
}
__device__ __forceinline__ float sigm(float z) { return 1.f / (1.f + __expf(-z)); }
__device__ __forceinline__ float tanh_f(float z) { float e = __expf(2.f * z); return 1.f - 2.f / (e + 1.f); }

__device__ __forceinline__ short8v cvt8(const float4 f0, const float4 f1) {
    short8v o;
    o[0]=(short)f2bf(f0.x); o[1]=(short)f2bf(f0.y); o[2]=(short)f2bf(f0.z); o[3]=(short)f2bf(f0.w);
    o[4]=(short)f2bf(f1.x); o[5]=(short)f2bf(f1.y); o[6]=(short)f2bf(f1.z); o[7]=(short)f2bf(f1.w);
    return o;
}

// ---------------------------------------------------------------------------
// Pack W = [W_ih | W_hh] into bf16 MFMA fragment order, q-major n-tiles:
// ntile = q*64 + jg -> W row = q*H + jg*16 + (lane&15), k = kk*32+(lane>>4)*8
// ---------------------------------------------------------------------------
__global__ void pack_w_kernel(const float* __restrict__ W_ih,
                              const float* __restrict__ W_hh,
                              unsigned short* __restrict__ wp) {
    int idx = blockIdx.x * 256 + threadIdx.x;
    if (idx >= 256 * KKT * 64) return;
    int lane  = idx & 63;
    int kk    = (idx >> 6) % KKT;
    int ntile = idx / (64 * KKT);
    int q = ntile >> 6;
    int orow = q * HH + (ntile & 63) * 16 + (lane & 15);
    int kbase = kk * 32 + (lane >> 4) * 8;
    short8v ov;
#pragma unroll
    for (int i = 0; i < 8; ++i) {
        int k = kbase + i;
        float v = (k < DD) ? W_ih[(size_t)orow * DD + k]
                           : W_hh[(size_t)orow * HH + (k - DD)];
        ov[i] = (short)f2bf(v);
    }
    *(short8v*)&wp[(size_t)idx * 8] = ov;
}

__global__ void pack_fc_kernel(const float* __restrict__ fc_w,
                               unsigned short* __restrict__ wfc) {
    int idx = blockIdx.x * 256 + threadIdx.x;
    if (idx >= NT_FC * KK_FC * 64) return;
    int lane  = idx & 63;
    int kk    = (idx >> 6) % KK_FC;
    int ntile = idx / (64 * KK_FC);
    int o = ntile * 16 + (lane & 15);
    int kbase = kk * 32 + (lane >> 4) * 8;
    short8v ov;
#pragma unroll
    for (int i = 0; i < 8; ++i)
        ov[i] = (short)f2bf(fc_w[(size_t)o * HH + kbase + i]);
    *(short8v*)&wfc[(size_t)idx * 8] = ov;
}

// x -> bf16 MFMA A-fragment order: xpre[((mtile*S + t)*16 + kk)*64 + lane]
// mtile = batch/16 = chain
__global__ void pack_x_kernel(const float* __restrict__ x,
                              unsigned short* __restrict__ xpre) {
    int idx = blockIdx.x * 256 + threadIdx.x;
    if (idx >= 8 * SS * 16 * 64) return;
    int lane  = idx & 63;
    int kk    = (idx >> 6) & 15;
    int t     = (idx >> 10) & (SS - 1);
    int mtile = idx >> 19;
    int b = mtile * 16 + (lane & 15);
    int d = kk * 32 + (lane >> 4) * 8;
    const float* src = &x[((size_t)b * SS + t) * DD + d];
    short8v ov;
#pragma unroll
    for (int i = 0; i < 8; ++i) ov[i] = (short)f2bf(src[i]);
    *(short8v*)&xpre[(size_t)idx * 8] = ov;
}

// zero h(0) + barrier slots, pack bias bp[j*4+q] = b_ih[q*H+j] + b_hh[q*H+j]
__global__ void init_kernel(const float* __restrict__ b_ih,
                            const float* __restrict__ b_hh,
                            unsigned short* __restrict__ h0,
                            float* __restrict__ bpp,
                            unsigned int* __restrict__ bar) {
    int i = blockIdx.x * 256 + threadIdx.x;
    if (i < BB * HH) h0[i] = 0;
    if (i < G4) { int j = i >> 2, q = i & 3; bpp[i] = b_ih[q * HH + j] + b_hh[q * HH + j]; }
    if (i < 4096) bar[i] = 0;
}

// ---------------------------------------------------------------------------
// Persistent LSTM: 512 WGs (2/CU) = 8 chains (16 batch rows) x 64 WGs (16 j).
// Wave = gate q, 1 ntile, M=16. W: kk0..15 VGPR, kk16..27 LDS, kk28..47 L2.
// HIST=1: every step writes a FRESH h buffer hh[t+1] (sc0/sc1 write-through);
// readers use normal CACHED loads. ANTI-PHASE SEED: chains 4..7 (co-resident
// with 0..3) start ~2.3us late so the CU's two WGs stall out of phase.
// ---------------------------------------------------------------------------
template<int PRE, int HIST>
__launch_bounds__(256, 2)
__global__ void lstm_persist(const float* __restrict__ x,
                             const unsigned short* __restrict__ xpre,
                             const unsigned short* __restrict__ wp,
                             const float* __restrict__ bp,
                             unsigned short* hh,          // HIST: base of SS+1 snapshots; else buf0
                             unsigned short* hbufB,       // HIST unused; else buf1
                             unsigned int* bar) {
    __shared__ __align__(16) unsigned short whl[4 * 12 * 64 * 8]; // 48 KiB W kk16..27
    __shared__ __align__(16) unsigned short hl[32 * 64 * 8];      // 32 KiB h frags (linear)
    float* gl = (float*)hl;                                       // gate exchange alias

    const int tid  = threadIdx.x;
    const int bid  = blockIdx.x;
    const int chain = bid >> 6;                 // 0..7 (16 batch rows each)
    const int jg    = bid & 63;                 // jg%8 = XCD for every chain
    const int lane = tid & 63;
    const int w    = tid >> 6;                  // wave = gate q
    const int l15  = lane & 15;
    const int lhi  = lane >> 4;

    // ---- resident W kk0..15 (64 VGPRs), pinned ----
    const size_t ntb = (size_t)(w * 64 + jg) * KKT;
    short8v wx[16];
#pragma unroll
    for (int kk = 0; kk < 16; ++kk)
        wx[kk] = *(const short8v*)&wp[((ntb + kk) * 64 + lane) * 8];
#pragma unroll
    for (int kk = 0; kk < 16; ++kk)
        asm volatile("" : "+v"(wx[kk]));

    // ---- LDS W kk16..27 (4 ntiles x 12 kk), loaded once ----
#pragma unroll
    for (int i = 0; i < 12; ++i) {
        int f  = tid + 256 * i;                 // 0..3071 16B frags
        int ln = f & 63, kkl = (f >> 6) % 12, wq = (f >> 6) / 12;
        *(short8v*)&whl[(size_t)f * 8] =
            *(const short8v*)&wp[(((size_t)(wq * 64 + jg) * KKT + 16 + kkl) * 64 + ln) * 8];
    }

    // ---- epilogue constants (tid < 128 active): row = tid>>3, units up,up+1 ----
    const int erow = (tid & 127) >> 3;
    const int eup  = (tid & 7) * 2;
    const float4 eb0 = *(const float4*)&bp[(jg * 16 + eup) * 4];
    const float4 eb1 = *(const float4*)&bp[(jg * 16 + eup + 1) * 4];
    float ec0 = 0.f, ec1 = 0.f;
    // frag-major h store offset (shorts) within a snapshot
    const int ekkh = jg >> 1;
    const int esub = (jg & 1) * 2 + (eup >> 3);
    const size_t esoff = ((size_t)(chain * 32 + ekkh) * 64 + (esub * 16 + erow)) * 8 + (eup & 7);

    __syncthreads();                            // whl ready

    // ---- anti-phase seed: stagger co-resident chain pairs by ~half a step ----
    if (chain >= 4) {
#pragma unroll 1
        for (int i = 0; i < 6; ++i) __builtin_amdgcn_s_sleep(15);
    }

#pragma unroll 1
    for (int t = 0; t < SS; ++t) {
        const unsigned short* hin;
        unsigned short* hout;
        if (HIST) {
            hin  = hh + (size_t)t * HSTEP;
            hout = hh + (size_t)(t + 1) * HSTEP;
        } else {
            hin  = (t & 1) ? hbufB : hh;
            hout = (t & 1) ? hh : hbufB;
        }

        __syncthreads();                        // S2: prev h stores acked by all

        // ---- arrive: publish "h(t-1) visible" ----
        if (t > 0 && tid == 0)
            __hip_atomic_store(&bar[chain * 64 + jg], (unsigned int)t,
                               __ATOMIC_RELAXED, __HIP_MEMORY_SCOPE_AGENT);

        float4v acce = {0.f, 0.f, 0.f, 0.f};
        float4v acco = {0.f, 0.f, 0.f, 0.f};

        // ---- x-phase (kk 0..15) — no h dependence, overlaps barrier ----
#pragma unroll
        for (int kk = 0; kk < 16; kk += 2) {
            short8v a0, a1;
            if (PRE) {
                a0 = *(const short8v*)&xpre[(((size_t)(chain * SS + t) * 16 + kk) * 64 + lane) * 8];
                a1 = *(const short8v*)&xpre[(((size_t)(chain * SS + t) * 16 + kk + 1) * 64 + lane) * 8];
            } else {
                const float* p0 = &x[((size_t)(chain * 16 + l15) * SS + t) * DD + kk * 32 + lhi * 8];
                a0 = cvt8(*(const float4*)p0, *(const float4*)(p0 + 4));
                a1 = cvt8(*(const float4*)(p0 + 32), *(const float4*)(p0 + 36));
            }
            acce = __builtin_amdgcn_mfma_f32_16x16x32_bf16(a0, wx[kk], acce, 0, 0, 0);
            acco = __builtin_amdgcn_mfma_f32_16x16x32_bf16(a1, wx[kk + 1], acco, 0, 0, 0);
        }

        // ---- barrier wait: wave 0 polls the chain's 64 packed slots ----
        if (t > 0 && w == 0) {
            const unsigned int tgt = (unsigned int)t;
            for (;;) {
                unsigned int v = __hip_atomic_load(&bar[chain * 64 + lane],
                                                   __ATOMIC_RELAXED, __HIP_MEMORY_SCOPE_AGENT);
                if (!__any(v < tgt)) break;
                __builtin_amdgcn_s_sleep(1);
            }
        }
        __syncthreads();                        // S3: h(t-1) globally visible

        // ---- stage h(t-1): identity copy, 128B/thread, conflict-free ----
        {
            const char* hsrc = (const char*)hin + (size_t)chain * 32768 + (size_t)tid * 16;
            char* ldst = (char*)hl + (size_t)tid * 16;
            if (HIST) {                         // normal cached loads: L2-shared per XCD
                uint4v r0 = *(const uint4v*)(hsrc);
                uint4v r1 = *(const uint4v*)(hsrc + 4096);
                uint4v r2 = *(const uint4v*)(hsrc + 8192);
                uint4v r3 = *(const uint4v*)(hsrc + 12288);
                uint4v r4 = *(const uint4v*)(hsrc + 16384);
                uint4v r5 = *(const uint4v*)(hsrc + 20480);
                uint4v r6 = *(const uint4v*)(hsrc + 24576);
                uint4v r7 = *(const uint4v*)(hsrc + 28672);
                *(uint4v*)(ldst)         = r0;
                *(uint4v*)(ldst + 4096)  = r1;
                *(uint4v*)(ldst + 8192)  = r2;
                *(uint4v*)(ldst + 12288) = r3;
                *(uint4v*)(ldst + 16384) = r4;
                *(uint4v*)(ldst + 20480) = r5;
                *(uint4v*)(ldst + 24576) = r6;
                *(uint4v*)(ldst + 28672) = r7;
            } else {                            // MALL-coherent fallback
                uint4v r0,r1,r2,r3,r4,r5,r6,r7;
                asm volatile("global_load_dwordx4 %0, %1, off sc0 sc1" : "=v"(r0) : "v"(hsrc));
                asm volatile("global_load_dwordx4 %0, %1, off sc0 sc1" : "=v"(r1) : "v"(hsrc + 4096));
                asm volatile("global_load_dwordx4 %0, %1, off sc0 sc1" : "=v"(r2) : "v"(hsrc + 8192));
                asm volatile("global_load_dwordx4 %0, %1, off sc0 sc1" : "=v"(r3) : "v"(hsrc + 12288));
                asm volatile("global_load_dwordx4 %0, %1, off sc0 sc1" : "=v"(r4) : "v"(hsrc + 16384));
                asm volatile("global_load_dwordx4 %0, %1, off sc0 sc1" : "=v"(r5) : "v"(hsrc + 20480));
                asm volatile("global_load_dwordx4 %0, %1, off sc0 sc1" : "=v"(r6) : "v"(hsrc + 24576));
                asm volatile("global_load_dwordx4 %0, %1, off sc0 sc1" : "=v"(r7) : "v"(hsrc + 28672));
                asm volatile("s_waitcnt vmcnt(0)" ::: "memory");
                __builtin_amdgcn_sched_barrier(0);
                *(uint4v*)(ldst)         = r0;
                *(uint4v*)(ldst + 4096)  = r1;
                *(uint4v*)(ldst + 8192)  = r2;
                *(uint4v*)(ldst + 12288) = r3;
                *(uint4v*)(ldst + 16384) = r4;
                *(uint4v*)(ldst + 20480) = r5;
                *(uint4v*)(ldst + 24576) = r6;
                *(uint4v*)(ldst + 28672) = r7;
            }
        }
        __syncthreads();                        // S4: hl ready

        // ---- h-phase (kkh 0..31 == kk 16..47), linear reads ----
#pragma unroll
        for (int kkh = 0; kkh < 32; kkh += 2) {
            short8v a0 = *(const short8v*)((char*)hl + kkh * 1024 + lane * 16);
            short8v a1 = *(const short8v*)((char*)hl + (kkh + 1) * 1024 + lane * 16);
            short8v b0, b1;
            if (kkh < 12) b0 = *(const short8v*)&whl[(size_t)((w * 12 + kkh) * 64 + lane) * 8];
            else          b0 = *(const short8v*)&wp[((ntb + 16 + kkh) * 64 + lane) * 8];
            if (kkh + 1 < 12) b1 = *(const short8v*)&whl[(size_t)((w * 12 + kkh + 1) * 64 + lane) * 8];
            else              b1 = *(const short8v*)&wp[((ntb + 16 + kkh + 1) * 64 + lane) * 8];
            acce = __builtin_amdgcn_mfma_f32_16x16x32_bf16(a0, b0, acce, 0, 0, 0);
            acco = __builtin_amdgcn_mfma_f32_16x16x32_bf16(a1, b1, acco, 0, 0, 0);
        }
        __syncthreads();                        // S5: hl dead -> gl alias safe

        // ---- gate exchange: gl[row][unit*4 + q] (16 x 68 floats) ----
#pragma unroll
        for (int r = 0; r < 4; ++r)
            gl[(lhi * 4 + r) * 68 + l15 * 4 + w] = acce[r] + acco[r];
        __syncthreads();                        // S6: gates ready

        // ---- fused activation + state (tid<128), frag-major h store + ack ----
        if (tid < 128) {
            float4 g0 = *(const float4*)&gl[erow * 68 + (eup + 0) * 4];
            float4 g1 = *(const float4*)&gl[erow * 68 + (eup + 1) * 4];
            float h0v, h1v;
            {
                float ig = sigm(g0.x + eb0.x), fg = sigm(g0.y + eb0.y);
                float gg = tanh_f(g0.z + eb0.z), og = sigm(g0.w + eb0.w);
                ec0 = fg * ec0 + ig * gg; h0v = og * tanh_f(ec0);
            }
            {
                float ig = sigm(g1.x + eb1.x), fg = sigm(g1.y + eb1.y);
                float gg = tanh_f(g1.z + eb1.z), og = sigm(g1.w + eb1.w);
                ec1 = fg * ec1 + ig * gg; h1v = og * tanh_f(ec1);
            }
            unsigned int hv = (unsigned int)f2bf(h0v) | ((unsigned int)f2bf(h1v) << 16);
            const unsigned short* hp = hout + esoff;
            asm volatile("global_store_dword %0, %1, off sc0 sc1"
                         :: "v"(hp), "v"(hv) : "memory");
        }
        asm volatile("s_waitcnt vmcnt(0)" ::: "memory");   // own store acked
    }
}

// ---------------------------------------------------------------------------
// out[128,1024] = h_fin @ fc_w^T + fc_b (fp32). hfin is FRAG-MAJOR.
// 32 WGs: 2 Mg x 16 Ng; no LDS needed.
// ---------------------------------------------------------------------------
__launch_bounds__(256)
__global__ void fc_kernel(const unsigned short* __restrict__ hfin,
                          const unsigned short* __restrict__ wfc,
                          const float* __restrict__ fc_b,
                          float* __restrict__ out) {
    const int tid = threadIdx.x, bid = blockIdx.x;
    const int mg = bid >> 4;
    const int ng = bid & 15;
    const int lane = tid & 63, wave = tid >> 6;
    const int wm = wave >> 1, wn = wave & 1;

    float4v acc[2][2] = {};
#pragma unroll
    for (int kkg = 0; kkg < 32; ++kkg) {
        short8v a[2], b[2];
#pragma unroll
        for (int mtl = 0; mtl < 2; ++mtl) {
            int gm = mg * 4 + wm * 2 + mtl;     // global 16-row tile 0..7
            a[mtl] = *(const short8v*)&hfin[((size_t)(gm * 32 + kkg) * 64 + lane) * 8];
        }
#pragma unroll
        for (int nt = 0; nt < 2; ++nt) {
            int ntile = ng * 4 + wn * 2 + nt;
            b[nt] = *(const short8v*)&wfc[(((size_t)ntile * KK_FC + kkg) * 64 + lane) * 8];
        }
#pragma unroll
        for (int mtl = 0; mtl < 2; ++mtl)
#pragma unroll
            for (int nt = 0; nt < 2; ++nt)
                acc[mtl][nt] = __builtin_amdgcn_mfma_f32_16x16x32_bf16(
                    a[mtl], b[nt], acc[mtl][nt], 0, 0, 0);
    }
#pragma unroll
    for (int mtl = 0; mtl < 2; ++mtl)
#pragma unroll
        for (int nt = 0; nt < 2; ++nt)
#pragma unroll
            for (int r = 0; r < 4; ++r) {
                int mrow = mg * 64 + wm * 32 + mtl * 16 + (lane >> 4) * 4 + r;
                int o = ng * 64 + wn * 32 + nt * 16 + (lane & 15);
                out[(size_t)mrow * HH + o] = acc[mtl][nt][r] + fc_b[o];
            }
}

// ---------------------------------------------------------------------------
extern "C" void kernel_launch(void* const* d_in, const int* in_sizes, int n_in,
                              void* d_out, int out_size, void* d_ws, size_t ws_size,
                              hipStream_t stream) {
    const float* x    = (const float*)d_in[0];
    const float* W_ih = (const float*)d_in[1];
    const float* W_hh = (const float*)d_in[2];
    const float* b_ih = (const float*)d_in[3];
    const float* b_hh = (const float*)d_in[4];
    const float* fc_w = (const float*)d_in[5];
    const float* fc_b = (const float*)d_in[6];
    float* out = (float*)d_out;

    char* ws = (char*)d_ws;
    size_t off = 0;
    unsigned short* wp  = (unsigned short*)(ws + off); off += (size_t)256 * KKT * 64 * 8 * 2;     // 12.6 MB
    unsigned short* wfc = (unsigned short*)(ws + off); off += (size_t)NT_FC * KK_FC * 64 * 8 * 2; // 2 MB
    float* bp  = (float*)(ws + off); off += (size_t)G4 * 4;
    unsigned int* bar = (unsigned int*)(ws + off); off += 4096 * 4;
    unsigned short* hbase = (unsigned short*)(ws + off);         // hist OR ping-pong
    size_t hist_bytes = (size_t)(SS + 1) * HSTEP * 2;            // 134.5 MB
    size_t pp_bytes   = (size_t)2 * HSTEP * 2;                   // 512 KB
    size_t xpre_bytes = (size_t)8 * SS * 16 * 64 * 8 * 2;        // 67 MB

    const bool hist = (ws_size >= off + hist_bytes);
    size_t hb = hist ? hist_bytes : pp_bytes;
    if (ws_size < off + hb) return;
    unsigned short* xpre = (unsigned short*)(ws + off + hb);
    const bool pre = (ws_size >= off + hb + xpre_bytes);

    unsigned short* hbufB = hist ? (unsigned short*)nullptr : (hbase + HSTEP);

    pack_w_kernel<<<3072, 256, 0, stream>>>(W_ih, W_hh, wp);
    pack_fc_kernel<<<512, 256, 0, stream>>>(fc_w, wfc);
    init_kernel<<<512, 256, 0, stream>>>(b_ih, b_hh, hbase, bp, bar);
    if (pre) pack_x_kernel<<<16384, 256, 0, stream>>>(x, xpre);

    if (hist) {
        if (pre) lstm_persist<1,1><<<512, 256, 0, stream>>>(x, xpre, wp, bp, hbase, hbufB, bar);
        else     lstm_persist<0,1><<<512, 256, 0, stream>>>(x, xpre, wp, bp, hbase, hbufB, bar);
    } else {
        if (pre) lstm_persist<1,0><<<512, 256, 0, stream>>>(x, xpre, wp, bp, hbase, hbufB, bar);
        else     lstm_persist<0,0><<<512, 256, 0, stream>>>(x, xpre, wp, bp, hbase, hbufB, bar);
    }

    // final h: hist -> snapshot SS; ping-pong (SS even) -> hbase
    const unsigned short* hfin = hist ? (hbase + (size_t)SS * HSTEP) : hbase;
    fc_kernel<<<32, 256, 0, stream>>>(hfin, wfc, fc_b, out);
}